// Round 1
// baseline (46.964 us; speedup 1.0000x reference)
//
#include <hip/hip_runtime.h>

// Problem constants (from reference setup_inputs)
#define BB_ 16
#define LL_ 2048
#define DD_ 512
#define CC_ 64            // chunks along L
#define TT_ (LL_ / CC_)   // 32 steps per chunk

// ---------------------------------------------------------------------------
// Kernel 1: fold gates into scan coefficients.
//   a[b,t]  = (1-p)(1-o)   (decay)
//   bb[b,t] = p(1-o)       (input coefficient)
// y_t = a_t * y_{t-1} + bb_t * x_t reproduces stack[:, -1, :] exactly.
// ---------------------------------------------------------------------------
__global__ void gates_kernel(const float* __restrict__ push,
                             const float* __restrict__ pop,
                             float* __restrict__ a_arr,
                             float* __restrict__ b_arr) {
    int i = blockIdx.x * blockDim.x + threadIdx.x;
    if (i < BB_ * LL_) {
        float p = push[i];
        float o = pop[i];
        float om = 1.0f - o;
        a_arr[i] = (1.0f - p) * om;
        b_arr[i] = p * om;
    }
}

// ---------------------------------------------------------------------------
// Kernel 2: per-(b,chunk) local scan with zero initial state.
// Writes chunk-end partial state yend[b,c,d] and chunk decay product Atot[b,c].
// Block = 128 threads, each owns 4 consecutive d (float4). Grid = B*C.
// ---------------------------------------------------------------------------
__global__ __launch_bounds__(128) void chunk_scan_kernel(
        const float* __restrict__ x,
        const float* __restrict__ a_arr,
        const float* __restrict__ b_arr,
        float* __restrict__ yend,
        float* __restrict__ Atot) {
    int blk = blockIdx.x;
    int b = blk / CC_;
    int c = blk % CC_;
    int t0 = c * TT_;
    int tid = threadIdx.x;  // 0..127

    __shared__ float sa[TT_];
    __shared__ float sb[TT_];
    if (tid < TT_)            sa[tid]       = a_arr[b * LL_ + t0 + tid];
    else if (tid < 2 * TT_)   sb[tid - TT_] = b_arr[b * LL_ + t0 + (tid - TT_)];
    __syncthreads();

    const float4* xp = (const float4*)(x + ((size_t)b * LL_ + t0) * DD_) + tid;
    float4 y = make_float4(0.f, 0.f, 0.f, 0.f);
    float pa = 1.0f;
    #pragma unroll
    for (int t = 0; t < TT_; ++t) {
        float4 xv = xp[(size_t)t * (DD_ / 4)];
        float a = sa[t];
        float g = sb[t];
        pa *= a;
        y.x = fmaf(a, y.x, g * xv.x);
        y.y = fmaf(a, y.y, g * xv.y);
        y.z = fmaf(a, y.z, g * xv.z);
        y.w = fmaf(a, y.w, g * xv.w);
    }
    ((float4*)(yend + ((size_t)b * CC_ + c) * DD_))[tid] = y;
    if (tid == 0) Atot[b * CC_ + c] = pa;
}

// ---------------------------------------------------------------------------
// Kernel 3: propagate carries across chunks (in place).
// After this, yend[b,c,d] holds the TRUE scan state entering chunk c.
// Grid = B blocks of 128 threads (float4 per thread). Sequential over C=64.
// ---------------------------------------------------------------------------
__global__ __launch_bounds__(128) void carry_kernel(
        float* __restrict__ yend,
        const float* __restrict__ Atot) {
    int b = blockIdx.x;
    int tid = threadIdx.x;
    float4* yp = (float4*)(yend + (size_t)b * CC_ * DD_) + tid;
    float4 carry = make_float4(0.f, 0.f, 0.f, 0.f);
    for (int c = 0; c < CC_; ++c) {
        float A = Atot[b * CC_ + c];
        float4 tmp = yp[(size_t)c * (DD_ / 4)];
        yp[(size_t)c * (DD_ / 4)] = carry;   // in-carry for chunk c
        carry.x = fmaf(A, carry.x, tmp.x);
        carry.y = fmaf(A, carry.y, tmp.y);
        carry.z = fmaf(A, carry.z, tmp.z);
        carry.w = fmaf(A, carry.w, tmp.w);
    }
}

// ---------------------------------------------------------------------------
// Kernel 4: final per-chunk scan seeded with the true in-carry; writes output.
// x is re-read (64 MiB, should be Infinity-Cache warm), out fully written.
// ---------------------------------------------------------------------------
__global__ __launch_bounds__(128) void final_scan_kernel(
        const float* __restrict__ x,
        const float* __restrict__ a_arr,
        const float* __restrict__ b_arr,
        const float* __restrict__ incarry,
        float* __restrict__ out) {
    int blk = blockIdx.x;
    int b = blk / CC_;
    int c = blk % CC_;
    int t0 = c * TT_;
    int tid = threadIdx.x;

    __shared__ float sa[TT_];
    __shared__ float sb[TT_];
    if (tid < TT_)            sa[tid]       = a_arr[b * LL_ + t0 + tid];
    else if (tid < 2 * TT_)   sb[tid - TT_] = b_arr[b * LL_ + t0 + (tid - TT_)];
    __syncthreads();

    const float4* xp = (const float4*)(x + ((size_t)b * LL_ + t0) * DD_) + tid;
    float4* op = (float4*)(out + ((size_t)b * LL_ + t0) * DD_) + tid;
    float4 y = ((const float4*)(incarry + ((size_t)b * CC_ + c) * DD_))[tid];

    #pragma unroll
    for (int t = 0; t < TT_; ++t) {
        float4 xv = xp[(size_t)t * (DD_ / 4)];
        float a = sa[t];
        float g = sb[t];
        y.x = fmaf(a, y.x, g * xv.x);
        y.y = fmaf(a, y.y, g * xv.y);
        y.z = fmaf(a, y.z, g * xv.z);
        y.w = fmaf(a, y.w, g * xv.w);
        op[(size_t)t * (DD_ / 4)] = y;
    }
}

extern "C" void kernel_launch(void* const* d_in, const int* in_sizes, int n_in,
                              void* d_out, int out_size, void* d_ws, size_t ws_size,
                              hipStream_t stream) {
    const float* x    = (const float*)d_in[0];
    const float* push = (const float*)d_in[1];
    const float* pop  = (const float*)d_in[2];
    float* out = (float*)d_out;

    // Workspace layout (floats):
    //   a_arr : B*L            = 32768
    //   b_arr : B*L            = 32768
    //   Atot  : B*C            = 1024
    //   yend  : B*C*D          = 524288   (becomes in-carries after carry_kernel)
    float* ws    = (float*)d_ws;
    float* a_arr = ws;
    float* b_arr = a_arr + (size_t)BB_ * LL_;
    float* Atot  = b_arr + (size_t)BB_ * LL_;
    float* yend  = Atot + (size_t)BB_ * CC_;

    gates_kernel<<<(BB_ * LL_ + 255) / 256, 256, 0, stream>>>(push, pop, a_arr, b_arr);
    chunk_scan_kernel<<<BB_ * CC_, 128, 0, stream>>>(x, a_arr, b_arr, yend, Atot);
    carry_kernel<<<BB_, 128, 0, stream>>>(yend, Atot);
    final_scan_kernel<<<BB_ * CC_, 128, 0, stream>>>(x, a_arr, b_arr, yend, out);
}

// Round 2
// 40.063 us; speedup vs baseline: 1.1723x; 1.1723x over previous
//
#include <hip/hip_runtime.h>

// Problem constants (from reference setup_inputs)
#define BB_ 16
#define LL_ 2048
#define DD_ 512
#define CC_ 64            // chunks along L
#define TT_ (LL_ / CC_)   // 32 steps per chunk

// Output y_t = stack[:, -1, :] obeys the first-order linear recurrence
//   y_t = a_t * y_{t-1} + g_t * x_t,   a = (1-p)(1-o),  g = p(1-o),  y_{-1}=0
// (slot 63's update only involves itself and the pushed value).
// Parallelized over L via chunked linear scan: 64 chunks of 32 steps.

// ---------------------------------------------------------------------------
// Kernel A: per-(b,chunk) local scan with zero initial state.
// Gates computed in-block from push/pop (no separate gates pass).
// Emits chunk-end partial state yend[b,c,d] and chunk decay product Atot[b,c].
// Block = 128 threads, each owns 4 consecutive d (float4). Grid = B*C = 1024.
// ---------------------------------------------------------------------------
__global__ __launch_bounds__(128) void chunk_scan_kernel(
        const float* __restrict__ x,
        const float* __restrict__ push,
        const float* __restrict__ pop,
        float* __restrict__ yend,
        float* __restrict__ Atot) {
    int blk = blockIdx.x;
    int b = blk / CC_;
    int c = blk % CC_;
    int t0 = c * TT_;
    int tid = threadIdx.x;  // 0..127

    __shared__ float sa[TT_];
    __shared__ float sb[TT_];
    if (tid < TT_) {
        float p = push[b * LL_ + t0 + tid];
        float o = pop[b * LL_ + t0 + tid];
        float om = 1.0f - o;
        sa[tid] = (1.0f - p) * om;
        sb[tid] = p * om;
    }
    __syncthreads();

    const float4* xp = (const float4*)(x + ((size_t)b * LL_ + t0) * DD_) + tid;
    float4 y = make_float4(0.f, 0.f, 0.f, 0.f);
    float pa = 1.0f;
    #pragma unroll
    for (int t = 0; t < TT_; ++t) {
        float4 xv = xp[(size_t)t * (DD_ / 4)];
        float a = sa[t];
        float g = sb[t];
        pa *= a;
        y.x = fmaf(a, y.x, g * xv.x);
        y.y = fmaf(a, y.y, g * xv.y);
        y.z = fmaf(a, y.z, g * xv.z);
        y.w = fmaf(a, y.w, g * xv.w);
    }
    ((float4*)(yend + ((size_t)b * CC_ + c) * DD_))[tid] = y;
    if (tid == 0) Atot[b * CC_ + c] = pa;
}

// ---------------------------------------------------------------------------
// Kernel B: fused carry-propagation + final scan.
// Each block (b,c) first reconstructs its in-carry serially:
//   y = 0;  for c' < c:  y = Atot[b,c'] * y + yend[b,c',:]
// (<=63 independent float4 loads from L2 pipelined under a short fma chain),
// then scans its chunk seeded with that carry, writing the output.
// x is re-read; it is 64 MiB and L3-resident from kernel A.
// ---------------------------------------------------------------------------
__global__ __launch_bounds__(128) void final_scan_kernel(
        const float* __restrict__ x,
        const float* __restrict__ push,
        const float* __restrict__ pop,
        const float* __restrict__ yend,
        const float* __restrict__ Atot,
        float* __restrict__ out) {
    int blk = blockIdx.x;
    int b = blk / CC_;
    int c = blk % CC_;
    int t0 = c * TT_;
    int tid = threadIdx.x;

    __shared__ float sa[TT_];
    __shared__ float sb[TT_];
    __shared__ float sA[CC_];
    if (tid < TT_) {
        float p = push[b * LL_ + t0 + tid];
        float o = pop[b * LL_ + t0 + tid];
        float om = 1.0f - o;
        sa[tid] = (1.0f - p) * om;
        sb[tid] = p * om;
    } else if (tid >= 64 && tid < 64 + CC_) {
        sA[tid - 64] = Atot[b * CC_ + (tid - 64)];
    }
    __syncthreads();

    // In-carry for chunk c.
    const float4* yp = (const float4*)(yend + (size_t)b * CC_ * DD_) + tid;
    float4 y = make_float4(0.f, 0.f, 0.f, 0.f);
    #pragma unroll 4
    for (int cp = 0; cp < c; ++cp) {
        float4 v = yp[(size_t)cp * (DD_ / 4)];
        float A = sA[cp];
        y.x = fmaf(A, y.x, v.x);
        y.y = fmaf(A, y.y, v.y);
        y.z = fmaf(A, y.z, v.z);
        y.w = fmaf(A, y.w, v.w);
    }

    // Final chunk scan, writing all outputs.
    const float4* xp = (const float4*)(x + ((size_t)b * LL_ + t0) * DD_) + tid;
    float4* op = (float4*)(out + ((size_t)b * LL_ + t0) * DD_) + tid;
    #pragma unroll
    for (int t = 0; t < TT_; ++t) {
        float4 xv = xp[(size_t)t * (DD_ / 4)];
        float a = sa[t];
        float g = sb[t];
        y.x = fmaf(a, y.x, g * xv.x);
        y.y = fmaf(a, y.y, g * xv.y);
        y.z = fmaf(a, y.z, g * xv.z);
        y.w = fmaf(a, y.w, g * xv.w);
        op[(size_t)t * (DD_ / 4)] = y;
    }
}

extern "C" void kernel_launch(void* const* d_in, const int* in_sizes, int n_in,
                              void* d_out, int out_size, void* d_ws, size_t ws_size,
                              hipStream_t stream) {
    const float* x    = (const float*)d_in[0];
    const float* push = (const float*)d_in[1];
    const float* pop  = (const float*)d_in[2];
    float* out = (float*)d_out;

    // Workspace layout (floats):
    //   Atot : B*C     = 1024
    //   yend : B*C*D   = 524288
    float* ws   = (float*)d_ws;
    float* Atot = ws;
    float* yend = Atot + (size_t)BB_ * CC_;

    chunk_scan_kernel<<<BB_ * CC_, 128, 0, stream>>>(x, push, pop, yend, Atot);
    final_scan_kernel<<<BB_ * CC_, 128, 0, stream>>>(x, push, pop, yend, Atot, out);
}